// Round 3
// baseline (206.809 us; speedup 1.0000x reference)
//
#include <hip/hip_runtime.h>

// DigitCaps dynamic routing, B=256 R=192 C=96 O=16 I=20. fp32 in/out.
// u_hat never materialized, NO split-K partials. 6 dispatches:
//   prep: W->WtT bf16 k-major; X->Xk + xT; bij=0 (c-major)
//   gemm1+squash (x3): 32m x 32n tile, full K=3840 as 30 steps of BK128.
//     T3+T4 pipeline: 3-deep LDS ring, raw s_barrier, counted
//     s_waitcnt vmcnt(8) -- loads stay in flight across barriers (never
//     drain to 0 in the loop). LDS tile in chunked [s][kq][row][8] layout:
//     ds_read_b128 frags AND staging writes are bank-conflict-free; the
//     global_load_lds SOURCE addresses are permuted to match (both-sides-
//     or-neither). B: it0 async; else reg-prefetch ring (3 sets) + wave-
//     local softmax scale at ds_write. Squash fused in epilogue
//     (16-lane butterfly; capsule's 16 o = one wave's frag columns).
//     Grid (48 n-tiles, 8 m-tiles): 8 m-blocks of one n-slice land on one
//     XCD (48%8==0) -> B slice L2-resident.
//   gemm2_agree (x2): 128x64 tile, grid (30,24), fully async staging;
//     agreement in epilogue vs WtT, atomicAdd bij
// Lesson R1: cross-block fusion via __threadfence = per-block L2 writeback
// storms. Lesson R2: __syncthreads-per-K-step = vmcnt(0) drain x30 = full
// load latency per step; fix = counted vmcnt + raw barriers (this round).

#define R_ 192
#define C_ 96
#define O_ 16
#define I_ 20
#define B_ 256
#define K1 3840   // R*I
#define N_ 1536   // C*O
#define NKT 30    // K1 / 128

typedef unsigned short u16;
typedef __attribute__((ext_vector_type(8))) short short8;
typedef __attribute__((ext_vector_type(4))) float floatx4;

__device__ inline float bf2f(u16 h) {
  union { unsigned int u; float f; } x; x.u = ((unsigned int)h) << 16; return x.f;
}
__device__ inline u16 f2bf(float f) {
  union { float f; unsigned int u; } x; x.f = f;
  unsigned int r = x.u + 0x7FFFu + ((x.u >> 16) & 1u);
  return (u16)(r >> 16);
}
__device__ inline unsigned int pack2(float a, float b) {
  return (unsigned int)f2bf(a) | ((unsigned int)f2bf(b) << 16);
}
// async 16B/lane global->LDS; lds base wave-uniform (lane scatters +16B)
__device__ inline void async16(const u16* g, u16* l) {
  __builtin_amdgcn_global_load_lds(
      (__attribute__((address_space(1))) void*)(unsigned long long)g,
      (__attribute__((address_space(3))) void*)(unsigned int)(unsigned long long)l,
      16, 0, 0);
}

// ---- fused prep: WtT gather (5760 blocks, 4 elems/thr); X cast+transpose
// (240); bij=0 c-major (18)
__global__ void k_prep(const float* __restrict__ W, const float* __restrict__ X,
                       u16* __restrict__ WtT, u16* __restrict__ Xk,
                       u16* __restrict__ xT, float* __restrict__ bij) {
  int bid = blockIdx.x;
  if (bid < 5760) {
    int t = (bid * 256 + threadIdx.x) << 2;    // 4-group stays in one n
    int n = t / K1, k = t - n * K1;
    int c = n >> 4, o = n & 15;
    const float* Wn = W + (size_t)(c * O_ + o) * I_;
    u16 h[4];
    #pragma unroll
    for (int e = 0; e < 4; ++e) {
      int ke = k + e, r = ke / I_, i = ke - r * I_;
      h[e] = f2bf(Wn[(size_t)r * (C_ * O_ * I_) + i]);
    }
    ushort4 o4; o4.x = h[0]; o4.y = h[1]; o4.z = h[2]; o4.w = h[3];
    *(ushort4*)&WtT[t] = o4;
  } else if (bid < 6000) {
    __shared__ u16 tile[64][72];
    int idx = bid - 5760;
    int kb = (idx % 60) << 6, bb = (idx / 60) << 6;
    int brow = threadIdx.x >> 4;          // 0..15
    int kq = (threadIdx.x & 15) << 2;     // 0..60 step 4
    #pragma unroll
    for (int p = 0; p < 4; ++p) {
      int bl = p * 16 + brow;
      float4 v = *(const float4*)(X + (size_t)(bb + bl) * K1 + kb + kq);
      ushort4 h;
      h.x = f2bf(v.x); h.y = f2bf(v.y); h.z = f2bf(v.z); h.w = f2bf(v.w);
      *(ushort4*)(Xk + (size_t)(bb + bl) * K1 + kb + kq) = h;
      tile[kq + 0][bl] = h.x;
      tile[kq + 1][bl] = h.y;
      tile[kq + 2][bl] = h.z;
      tile[kq + 3][bl] = h.w;
    }
    __syncthreads();
    int kr = threadIdx.x >> 3;            // 0..31
    int bq = (threadIdx.x & 7) << 3;      // 0..56 step 8
    #pragma unroll
    for (int q = 0; q < 2; ++q) {
      int kl = q * 32 + kr;
      *(uint4*)(xT + (size_t)(kb + kl) * B_ + bb + bq) = *(const uint4*)&tile[kl][bq];
    }
  } else {
    int t = ((bid - 6000) * 256 + threadIdx.x) << 2;  // bij: 18,432 floats
    if (t < R_ * C_) *(float4*)&bij[t] = (float4){0.f, 0.f, 0.f, 0.f};
  }
}

// scale 8 k-contiguous bf16 (global k = kg..kg+7) by softmax row(s)
__device__ inline uint4 scale_b8(uint4 raw, int kg, const float* smrow) {
  int r0 = kg / I_;
  int bnd = (r0 + 1) * I_ - kg;                // elements j<bnd use r0
  float s0 = smrow[r0];
  float s1 = smrow[(r0 + 1 < R_) ? r0 + 1 : R_ - 1];
  union { uint4 q; u16 h[8]; } u; u.q = raw;
  #pragma unroll
  for (int j = 0; j < 8; ++j)
    u.h[j] = f2bf(bf2f(u.h[j]) * ((j < bnd) ? s0 : s1));
  return u.q;
}

// ---- GEMM1 + fused squash, pipelined. s[32b x 32n], full K=3840.
// 4 waves 2x2, each one 16x16 MFMA quadrant (= one capsule's 16 o).
// LDS layout per buffer: chunk(s,kq,row) = (s*4+kq)*32+row, 8 u16/chunk
// (s = 32-k subtile 0..3, kq = 8-k group 0..3, row 0..31). Frag read:
// lane(quad,lrow) reads chunk (s*4+quad)*32+row -> sequential 16B chunks
// per wave -> conflict-free. Staging: call m covers chunks m*256+w*64+l;
// source k = s*32+kq*8 derived per lane (pre-swizzled global source).
__global__ __launch_bounds__(256, 3) void gemm1(
    const u16* __restrict__ A, const u16* __restrict__ Bt,
    const float* __restrict__ bij, int doScale,
    float* __restrict__ out, u16* __restrict__ vT,
    float preScale, int last) {
  __shared__ u16 As[3][4096];      // 3 x 8 KB ring
  __shared__ u16 Bs[3][4096];      // 3 x 8 KB ring
  __shared__ float sm[2][192];     // 1.5 KB
  int tid = threadIdx.x;
  int w = tid >> 6, lane = tid & 63;
  if (doScale && w < 2) {  // wave w owns capsule 2*bx + w (softmax over 192 r)
    int c = ((int)blockIdx.x << 1) + w;
    float e0 = bij[c * R_ + lane];
    float e1 = bij[c * R_ + lane + 64];
    float e2 = bij[c * R_ + lane + 128];
    float mx = fmaxf(e0, fmaxf(e1, e2));
    #pragma unroll
    for (int off = 32; off > 0; off >>= 1) mx = fmaxf(mx, __shfl_xor(mx, off));
    e0 = expf(e0 - mx); e1 = expf(e1 - mx); e2 = expf(e2 - mx);
    float s = e0 + e1 + e2;
    #pragma unroll
    for (int off = 32; off > 0; off >>= 1) s += __shfl_xor(s, off);
    float inv = 1.0f / s;
    sm[w][lane] = e0 * inv;
    sm[w][lane + 64] = e1 * inv;
    sm[w][lane + 128] = e2 * inv;
  }

  long n0 = (long)blockIdx.x * 32, m0 = (long)blockIdx.y * 32;
  const u16* Ab = A + m0 * K1;
  const u16* Bb = Bt + n0 * K1;
  // staging: call m, wave w, lane l -> chunk id = m*256 + w*64 + l
  //   s = m*2 + (w>>1); kq = (2w + (l>>5)) & 3; row = l & 31
  int l31 = lane & 31;
  int aS = w >> 1;
  int aK = ((w << 1) + (lane >> 5)) & 3;
  const u16* AgA = Ab + (long)l31 * K1 + aS * 32 + aK * 8;  // m=0; m=1 = +64
  const u16* BgA = Bb + (long)l31 * K1 + aS * 32 + aK * 8;
  int ldsLo = w << 9;              // chunk (w*64)*8 u16
  int ldsHi = 2048 + (w << 9);     // call m=1
  // doScale reg-staging: thread -> (row=tid&31, kq16=tid>>5 and +8)
  int rowb = tid & 31;
  int kq = tid >> 5;               // 0..7
  const u16* Bgs = Bb + (long)rowb * K1 + kq * 8;
  int wA0 = ((((kq) >> 2) << 7) + (((kq) & 3) << 5) + rowb) << 3;    // = tid*8
  int wA1 = ((((kq + 8) >> 2) << 7) + (((kq + 8) & 3) << 5) + rowb) << 3;
  const float* smrow = &sm[rowb >> 4][0];
  int kgB0 = kq << 3, kgB1 = (kq + 8) << 3;
  // frag reads: lane(quad,lrow) -> chunk (s*4+quad)*32 + (wm/wn + lrow)
  int wm = (w >> 1) << 4, wn = (w & 1) << 4;
  int quad = lane >> 4, lrow = lane & 15;
  int rdA = (quad << 8) + ((wm + lrow) << 3);   // + s*1024
  int rdB = (quad << 8) + ((wn + lrow) << 3);
  floatx4 acc = (floatx4){0.f, 0.f, 0.f, 0.f};
  uint4 pb00, pb01, pb10, pb11, pb20, pb21;

  // prologue: stage buffers 0..2 (kt=0,1,2), then one full drain
  async16(AgA, &As[0][ldsLo]);
  async16(AgA + 64, &As[0][ldsHi]);
  async16(AgA + 128, &As[1][ldsLo]);
  async16(AgA + 192, &As[1][ldsHi]);
  async16(AgA + 256, &As[2][ldsLo]);
  async16(AgA + 320, &As[2][ldsHi]);
  if (doScale) {
    pb00 = *(const uint4*)(Bgs);       pb01 = *(const uint4*)(Bgs + 64);
    pb10 = *(const uint4*)(Bgs + 128); pb11 = *(const uint4*)(Bgs + 192);
    pb20 = *(const uint4*)(Bgs + 256); pb21 = *(const uint4*)(Bgs + 320);
  } else {
    async16(BgA, &Bs[0][ldsLo]);       async16(BgA + 64, &Bs[0][ldsHi]);
    async16(BgA + 128, &Bs[1][ldsLo]); async16(BgA + 192, &Bs[1][ldsHi]);
    async16(BgA + 256, &Bs[2][ldsLo]); async16(BgA + 320, &Bs[2][ldsHi]);
  }
  __syncthreads();                 // drain staging (once); sm visible

  // per step: wait own buf-kt loads (counted vmcnt, never 0 mid-loop),
  // [doScale: scale+ds_write B, lgkm0], barrier#1 (all waves' data in),
  // ds_read 8 frags, lgkm0, barrier#2 (buf free), prefetch kt+3, 4 MFMA.
#define G1_STEP(BUF, PB0, PB1, VM, DOPF)                                   \
  {                                                                        \
    asm volatile("s_waitcnt vmcnt(" #VM ")" ::: "memory");                 \
    if (doScale) {                                                         \
      *(uint4*)&Bs[BUF][wA0] = scale_b8(PB0, kOff + kgB0, smrow);          \
      *(uint4*)&Bs[BUF][wA1] = scale_b8(PB1, kOff + kgB1, smrow);          \
      asm volatile("s_waitcnt lgkmcnt(0)" ::: "memory");                   \
    }                                                                      \
    __builtin_amdgcn_s_barrier();                                          \
    short8 af0 = *(const short8*)&As[BUF][rdA];                            \
    short8 af1 = *(const short8*)&As[BUF][rdA + 1024];                     \
    short8 af2 = *(const short8*)&As[BUF][rdA + 2048];                     \
    short8 af3 = *(const short8*)&As[BUF][rdA + 3072];                     \
    short8 bf0 = *(const short8*)&Bs[BUF][rdB];                            \
    short8 bf1 = *(const short8*)&Bs[BUF][rdB + 1024];                     \
    short8 bf2 = *(const short8*)&Bs[BUF][rdB + 2048];                     \
    short8 bf3 = *(const short8*)&Bs[BUF][rdB + 3072];                     \
    asm volatile("s_waitcnt lgkmcnt(0)" ::: "memory");                     \
    __builtin_amdgcn_sched_barrier(0);                                     \
    __builtin_amdgcn_s_barrier();                                          \
    if (DOPF) {                                                            \
      async16(AgA + kOff + 384, &As[BUF][ldsLo]);                          \
      async16(AgA + kOff + 448, &As[BUF][ldsHi]);                          \
      if (doScale) {                                                       \
        PB0 = *(const uint4*)(Bgs + kOff + 384);                           \
        PB1 = *(const uint4*)(Bgs + kOff + 448);                           \
      } else {                                                             \
        async16(BgA + kOff + 384, &Bs[BUF][ldsLo]);                        \
        async16(BgA + kOff + 448, &Bs[BUF][ldsHi]);                        \
      }                                                                    \
    }                                                                      \
    acc = __builtin_amdgcn_mfma_f32_16x16x32_bf16(af0, bf0, acc, 0, 0, 0); \
    acc = __builtin_amdgcn_mfma_f32_16x16x32_bf16(af1, bf1, acc, 0, 0, 0); \
    acc = __builtin_amdgcn_mfma_f32_16x16x32_bf16(af2, bf2, acc, 0, 0, 0); \
    acc = __builtin_amdgcn_mfma_f32_16x16x32_bf16(af3, bf3, acc, 0, 0, 0); \
    kOff += 128;                                                           \
  }

  int kOff = 0;
  #pragma unroll 1
  for (int c3 = 0; c3 < 9; ++c3) {     // kt = 0..26, all prefetch kt+3
    G1_STEP(0, pb00, pb01, 8, 1)
    G1_STEP(1, pb10, pb11, 8, 1)
    G1_STEP(2, pb20, pb21, 8, 1)
  }
  G1_STEP(0, pb00, pb01, 8, 0)         // kt=27
  G1_STEP(1, pb10, pb11, 4, 0)         // kt=28
  G1_STEP(2, pb20, pb21, 0, 0)         // kt=29
#undef G1_STEP

  // ---- fused squash. Wave holds 16 b x 16 o of ONE capsule.
  // C/D layout: col(o) = lane&15, row(b) = quad*4 + e.
  float v0 = acc[0] * preScale, v1 = acc[1] * preScale;
  float v2 = acc[2] * preScale, v3 = acc[3] * preScale;
  float q0 = v0 * v0, q1 = v1 * v1, q2 = v2 * v2, q3 = v3 * v3;
  #pragma unroll
  for (int off = 1; off < 16; off <<= 1) {   // sum over 16 o-columns
    q0 += __shfl_xor(q0, off);
    q1 += __shfl_xor(q1, off);
    q2 += __shfl_xor(q2, off);
    q3 += __shfl_xor(q3, off);
  }
  v0 *= q0 / ((1.0f + q0) * sqrtf(q0));
  v1 *= q1 / ((1.0f + q1) * sqrtf(q1));
  v2 *= q2 / ((1.0f + q2) * sqrtf(q2));
  v3 *= q3 / ((1.0f + q3) * sqrtf(q3));
  int n = (int)n0 + wn + lrow;
  int b = (int)m0 + wm + (quad << 2);
  if (last) {
    out[(size_t)(b + 0) * N_ + n] = v0;
    out[(size_t)(b + 1) * N_ + n] = v1;
    out[(size_t)(b + 2) * N_ + n] = v2;
    out[(size_t)(b + 3) * N_ + n] = v3;
  } else {
    uint2 pk;
    pk.x = pack2(v0, v1);
    pk.y = pack2(v2, v3);
    *(uint2*)&vT[(size_t)n * B_ + b] = pk;
  }
}

// ---- GEMM2 + agreement fused, 128m x 64n tile, grid (30,24), K=256 =
// 4 x BK64 (2 BK32 sub-tiles per barrier), fully async staging.
__global__ __launch_bounds__(256) void gemm2_agree(
    const u16* __restrict__ A, const u16* __restrict__ Bt,
    const u16* __restrict__ WtT, float* __restrict__ bij) {
  const int K = 256;
  __shared__ u16 As[2][2][128 * 32];
  __shared__ u16 Bs[2][2][64 * 32];
  int tid = threadIdx.x;
  long m0 = (long)blockIdx.x * 128, n0 = (long)blockIdx.y * 64;
  const u16* Ab = A + m0 * K;
  const u16* Bb = Bt + n0 * K;
  int srow = tid >> 2;
  int scol = (tid & 3) << 3;
  int w = tid >> 6, lane = tid & 63;
  int wm = (w >> 1) << 6, wn = (w & 1) << 5;
  int quad = lane >> 4, lrow = lane & 15;
  int wb = w << 9;                  // wave-uniform LDS base (u16 elems)
  const u16* Ag0 = Ab + (long)srow * K + scol;
  const u16* Ag1 = Ab + (long)(srow + 64) * K + scol;
  const u16* Bg0 = Bb + (long)srow * K + scol;
  floatx4 acc[4][2];
  #pragma unroll
  for (int a = 0; a < 4; ++a)
    #pragma unroll
    for (int b = 0; b < 2; ++b) acc[a][b] = (floatx4){0.f, 0.f, 0.f, 0.f};

  async16(Ag0, &As[0][0][wb]);
  async16(Ag1, &As[0][0][2048 + wb]);
  async16(Ag0 + 32, &As[0][1][wb]);
  async16(Ag1 + 32, &As[0][1][2048 + wb]);
  async16(Bg0, &Bs[0][0][wb]);
  async16(Bg0 + 32, &Bs[0][1][wb]);

  int p = 0;
  #pragma unroll
  for (int kt = 0; kt < 4; ++kt) {
    __syncthreads();                 // buf p asyncs complete
    if (kt + 1 < 4) {                // async prefetch escapes the drain
      int kk = (kt + 1) << 6;
      async16(Ag0 + kk, &As[p ^ 1][0][wb]);
      async16(Ag1 + kk, &As[p ^ 1][0][2048 + wb]);
      async16(Ag0 + kk + 32, &As[p ^ 1][1][wb]);
      async16(Ag1 + kk + 32, &As[p ^ 1][1][2048 + wb]);
      async16(Bg0 + kk, &Bs[p ^ 1][0][wb]);
      async16(Bg0 + kk + 32, &Bs[p ^ 1][1][wb]);
    }
    #pragma unroll
    for (int s = 0; s < 2; ++s) {
      short8 af[4], bfr[2];
      #pragma unroll
      for (int ms = 0; ms < 4; ++ms)
        af[ms] = *(const short8*)&As[p][s][(wm + ms * 16 + lrow) * 32 + (quad << 3)];
      #pragma unroll
      for (int ns = 0; ns < 2; ++ns)
        bfr[ns] = *(const short8*)&Bs[p][s][(wn + ns * 16 + lrow) * 32 + (quad << 3)];
      #pragma unroll
      for (int ms = 0; ms < 4; ++ms)
        #pragma unroll
        for (int ns = 0; ns < 2; ++ns)
          acc[ms][ns] = __builtin_amdgcn_mfma_f32_16x16x32_bf16(
              af[ms], bfr[ns], acc[ms][ns], 0, 0, 0);
    }
    p ^= 1;
  }
  // epilogue: per fragment, cols = one capsule c; 16 rows span <=2 routes r.
  #pragma unroll
  for (int ms = 0; ms < 4; ++ms) {
    int rowbase = (int)m0 + wm + ms * 16;          // wave-uniform
    int r_lo = rowbase / I_;
    int r_hi = (rowbase + 15) / I_;
    int bnd = (r_lo + 1) * I_;
    int rowl = rowbase + (quad << 2);
    #pragma unroll
    for (int ns = 0; ns < 2; ++ns) {
      int col = (int)n0 + wn + ns * 16 + lrow;
      uint2 wv = *(const uint2*)&WtT[(size_t)col * K1 + rowl];
      u16 h[4];
      h[0] = (u16)(wv.x & 0xffff); h[1] = (u16)(wv.x >> 16);
      h[2] = (u16)(wv.y & 0xffff); h[3] = (u16)(wv.y >> 16);
      float p0 = 0.f, p1 = 0.f;
      #pragma unroll
      for (int e = 0; e < 4; ++e) {
        float pr = acc[ms][ns][e] * bf2f(h[e]);
        if (rowl + e < bnd) p0 += pr; else p1 += pr;
      }
      #pragma unroll
      for (int off = 32; off > 0; off >>= 1) {
        p0 += __shfl_xor(p0, off);
        p1 += __shfl_xor(p1, off);
      }
      if (lane == 0) {
        int c = col >> 4;
        atomicAdd(&bij[c * R_ + r_lo], p0 * (1.0f / 256.0f));
        atomicAdd(&bij[c * R_ + r_hi], p1 * (1.0f / 256.0f));
      }
    }
  }
}

extern "C" void kernel_launch(void* const* d_in, const int* in_sizes, int n_in,
                              void* d_out, int out_size, void* d_ws, size_t ws_size,
                              hipStream_t stream) {
  const float* X = (const float*)d_in[0];   // fp32 [256,192,20]
  const float* W = (const float*)d_in[1];   // fp32 [192,96,16,20]
  float* out = (float*)d_out;               // fp32 [256,96,16]
  char* ws = (char*)d_ws;
  u16*  WtT = (u16*)(ws);                   // 11,796,480 B
  u16*  Xk  = (u16*)(ws + 11796480);        //  1,966,080 B
  u16*  xT  = (u16*)(ws + 13762560);        //  1,966,080 B
  u16*  vT  = (u16*)(ws + 15728640);        //    786,432 B
  float* bij = (float*)(ws + 16515072);     //     73,728 B (c-major [c][r])

  k_prep<<<6018, 256, 0, stream>>>(W, X, WtT, Xk, xT, bij);

  for (int it = 0; it < 3; ++it) {
    // s_j + squash in one kernel: M=256,N=1536,K=3840 full-K, grid (48,8).
    // iter 0: no scale in gemm1; uniform softmax 1/192 via preScale.
    gemm1<<<dim3(48, 8), 256, 0, stream>>>(
        Xk, WtT, bij, it > 0, out, vT,
        it == 0 ? (1.0f / 192.0f) : 1.0f, it == 2 ? 1 : 0);
    if (it < 2)
      gemm2_agree<<<dim3(30, 24), 256, 0, stream>>>(xT, vT, WtT, bij);
  }
}

// Round 4
// 174.069 us; speedup vs baseline: 1.1881x; 1.1881x over previous
//
#include <hip/hip_runtime.h>

// DigitCaps dynamic routing, B=256 R=192 C=96 O=16 I=20. fp32 in/out.
// u_hat never materialized. 9 dispatches (R0 proven structure) + T2 layout:
//   prep: W->WtT bf16 k-major; X->Xk + xT; bij=0 (bij C-MAJOR [c][r])
//   gemm1 (x3): 128m x 64n tile, split-K=15 (kChunk 256 = 4 iters of BK64,
//     each iter = 2 BK32 sub-tiles sharing ONE barrier), grid (2,24,15)=720;
//     A async global_load_lds(16B); B: it0 fully async, else reg-prefetch +
//     wave-local softmax scale at LDS-write; double LDS; partials bf16
//     P^T[z][n][b]
//   redsq (x3): grid (96,4); split-K reduce (+preScale) + squash -> vT/out
//   gemm2_agree (x2): 128x64 tile, grid (30,24), fully async staging;
//     agreement in epilogue vs WtT, atomicAdd bij
// NEW vs R0: LDS tiles in chunked [sub][kquad][row][16B] order. Frag
// ds_read_b128: 16-lane groups read 256B contiguous -> conflict-free (was
// 8-way: 64B row stride, 8.4M SQ_LDS_BANK_CONFLICT/dispatch). Staging keeps
// LDS dest linear (global_load_lds requirement) and permutes the GLOBAL
// source address instead (both-sides-or-neither). ds_write scale path
// writes consecutive 16B per lane -> conflict-free.
// Lesson R1: __threadfence cross-block fusion = L2-writeback storm.
// Lesson R2/R3: 32x32 full-K tile = 2x L2/L3 traffic, BW-bound; pipelining
// null in that regime. Split-K + high TLP is the right shape.

#define R_ 192
#define C_ 96
#define O_ 16
#define I_ 20
#define B_ 256
#define K1 3840   // R*I
#define N_ 1536   // C*O
#define ZSPLIT 15
#define KCH 256       // K1/ZSPLIT; 4 iters of BK=64 (2x BK32 sub-tiles)
#define STILE 393216  // N_*B_ elements per z-slice

typedef unsigned short u16;
typedef __attribute__((ext_vector_type(8))) short short8;
typedef __attribute__((ext_vector_type(4))) float floatx4;

__device__ inline float bf2f(u16 h) {
  union { unsigned int u; float f; } x; x.u = ((unsigned int)h) << 16; return x.f;
}
__device__ inline u16 f2bf(float f) {
  union { float f; unsigned int u; } x; x.f = f;
  unsigned int r = x.u + 0x7FFFu + ((x.u >> 16) & 1u);
  return (u16)(r >> 16);
}
__device__ inline unsigned int pack2(float a, float b) {
  return (unsigned int)f2bf(a) | ((unsigned int)f2bf(b) << 16);
}
// async 16B/lane global->LDS; lds base wave-uniform (lane scatters +16B)
__device__ inline void async16(const u16* g, u16* l) {
  __builtin_amdgcn_global_load_lds(
      (__attribute__((address_space(1))) void*)(unsigned long long)g,
      (__attribute__((address_space(3))) void*)(unsigned int)(unsigned long long)l,
      16, 0, 0);
}

// ---- fused prep: WtT gather (5760 blocks, 4 elems/thr); X cast+transpose
// (240); bij=0 c-major (18)
__global__ void k_prep(const float* __restrict__ W, const float* __restrict__ X,
                       u16* __restrict__ WtT, u16* __restrict__ Xk,
                       u16* __restrict__ xT, float* __restrict__ bij) {
  int bid = blockIdx.x;
  if (bid < 5760) {
    int t = (bid * 256 + threadIdx.x) << 2;    // 4-group stays in one n
    int n = t / K1, k = t - n * K1;
    int c = n >> 4, o = n & 15;
    const float* Wn = W + (size_t)(c * O_ + o) * I_;
    u16 h[4];
    #pragma unroll
    for (int e = 0; e < 4; ++e) {
      int ke = k + e, r = ke / I_, i = ke - r * I_;
      h[e] = f2bf(Wn[(size_t)r * (C_ * O_ * I_) + i]);
    }
    ushort4 o4; o4.x = h[0]; o4.y = h[1]; o4.z = h[2]; o4.w = h[3];
    *(ushort4*)&WtT[t] = o4;
  } else if (bid < 6000) {
    __shared__ u16 tile[64][72];
    int idx = bid - 5760;
    int kb = (idx % 60) << 6, bb = (idx / 60) << 6;
    int brow = threadIdx.x >> 4;          // 0..15
    int kq = (threadIdx.x & 15) << 2;     // 0..60 step 4
    #pragma unroll
    for (int p = 0; p < 4; ++p) {
      int bl = p * 16 + brow;
      float4 v = *(const float4*)(X + (size_t)(bb + bl) * K1 + kb + kq);
      ushort4 h;
      h.x = f2bf(v.x); h.y = f2bf(v.y); h.z = f2bf(v.z); h.w = f2bf(v.w);
      *(ushort4*)(Xk + (size_t)(bb + bl) * K1 + kb + kq) = h;
      tile[kq + 0][bl] = h.x;
      tile[kq + 1][bl] = h.y;
      tile[kq + 2][bl] = h.z;
      tile[kq + 3][bl] = h.w;
    }
    __syncthreads();
    int kr = threadIdx.x >> 3;            // 0..31
    int bq = (threadIdx.x & 7) << 3;      // 0..56 step 8
    #pragma unroll
    for (int q = 0; q < 2; ++q) {
      int kl = q * 32 + kr;
      *(uint4*)(xT + (size_t)(kb + kl) * B_ + bb + bq) = *(const uint4*)&tile[kl][bq];
    }
  } else {
    int t = ((bid - 6000) * 256 + threadIdx.x) << 2;  // bij: 18,432 floats
    if (t < R_ * C_) *(float4*)&bij[t] = (float4){0.f, 0.f, 0.f, 0.f};
  }
}

// scale 8 k-contiguous bf16 (global k = kg..kg+7) by softmax row(s)
__device__ inline uint4 scale_b8(uint4 raw, int kg, const float* smrow) {
  int r0 = kg / I_;
  int bnd = (r0 + 1) * I_ - kg;                // elements j<bnd use r0
  float s0 = smrow[r0];
  float s1 = smrow[(r0 + 1 < R_) ? r0 + 1 : R_ - 1];
  union { uint4 q; u16 h[8]; } u; u.q = raw;
  #pragma unroll
  for (int j = 0; j < 8; ++j)
    u.h[j] = f2bf(bf2f(u.h[j]) * ((j < bnd) ? s0 : s1));
  return u.q;
}

// LDS chunk layout (per buffer):
//   A elem(sub,quad,row,j) -> sub*4096 + quad*1024 + row*8 + j   (row<128)
//   B elem(sub,quad,row,j) -> sub*2048 + quad*512  + row*8 + j   (row<64)
// (sub = 32-k subtile 0/1, quad = 8-k group 0..3, j = k within 8.)
// Frag read lane(quad=lane>>4,lrow): 16 lanes -> 256B contiguous. Staging
// call covers 64 consecutive chunks; source row/col derived per call.

// ---- GEMM1: P^T[z][n][b] bf16 = (Xk[256,3840] x (c*WtT)[1536,3840]^T),
// k-chunk z (256 = 4 x BK64; each BK64 = 2 BK32 sub-tiles, ONE barrier).
// 128m x 64n tile, 4 waves of 64x32, grid (2,24,15)=720.
__global__ __launch_bounds__(256) void gemm1(
    const u16* __restrict__ A, const u16* __restrict__ Bt,
    const float* __restrict__ bij, u16* __restrict__ P, int doScale) {
  __shared__ u16 As[2][8192];   // 32 KB (chunked)
  __shared__ u16 Bs[2][4096];   // 16 KB (chunked)
  __shared__ float sm[4][192];
  int tid = threadIdx.x;
  int w = tid >> 6, lane = tid & 63;
  if (doScale) {  // wave-local softmax: wave w owns capsule (by<<2)+w
    int c = (blockIdx.y << 2) + w;
    float e0 = bij[c * R_ + lane];
    float e1 = bij[c * R_ + lane + 64];
    float e2 = bij[c * R_ + lane + 128];
    float mx = fmaxf(e0, fmaxf(e1, e2));
    #pragma unroll
    for (int off = 32; off > 0; off >>= 1) mx = fmaxf(mx, __shfl_xor(mx, off));
    e0 = expf(e0 - mx); e1 = expf(e1 - mx); e2 = expf(e2 - mx);
    float s = e0 + e1 + e2;
    #pragma unroll
    for (int off = 32; off > 0; off >>= 1) s += __shfl_xor(s, off);
    float inv = 1.0f / s;
    sm[w][lane] = e0 * inv;
    sm[w][lane + 64] = e1 * inv;
    sm[w][lane + 128] = e2 * inv;
  }

  long m0 = (long)blockIdx.x * 128, n0 = (long)blockIdx.y * 64;
  int k0 = blockIdx.z * KCH;
  const u16* Ab = A + m0 * K1 + k0;
  const u16* Bb = Bt + n0 * K1 + k0;
  // A staging: 16 wave-calls cover chunks; call m of wave w = chunk group
  // g16=(m<<2)+w: sub=g16>>3, quad=(g16>>1)&3, rowHalf=(g16&1)*64.
  const u16* AgC[4]; int AlC[4];
  #pragma unroll
  for (int m = 0; m < 4; ++m) {
    int g16 = (m << 2) + w;
    AgC[m] = Ab + (long)(((g16 & 1) << 6) + lane) * K1
             + (g16 >> 3) * 32 + ((g16 >> 1) & 3) * 8;
    AlC[m] = g16 << 9;                 // elem base (g16*512)
  }
  // B staging (async, it0): 8 wave-calls, g8=(m<<2)+w: sub=g8>>2, quad=g8&3.
  const u16* BgC[2]; int BlC[2];
  #pragma unroll
  for (int m = 0; m < 2; ++m) {
    int g8 = (m << 2) + w;
    BgC[m] = Bb + (long)lane * K1 + (g8 >> 2) * 32 + (g8 & 3) * 8;
    BlC[m] = g8 << 9;
  }
  // doScale reg-staging: thread = chunk tid of sub0 (+ same of sub1):
  // row = tid&63, quad = tid>>6 (=w); writes consecutive 16B -> no conflict.
  const u16* Bgs = Bb + (long)(tid & 63) * K1 + (w << 3);
  const float* smrow = &sm[(tid & 63) >> 4][0];
  int wm = (w >> 1) << 6, wn = (w & 1) << 5;
  int quad = lane >> 4, lrow = lane & 15;
  floatx4 acc[4][2];
  #pragma unroll
  for (int a = 0; a < 4; ++a)
    #pragma unroll
    for (int b = 0; b < 2; ++b) acc[a][b] = (floatx4){0.f, 0.f, 0.f, 0.f};

  // kt=0 staging: both sub-tiles
  #pragma unroll
  for (int m = 0; m < 4; ++m) async16(AgC[m], &As[0][AlC[m]]);
  uint4 b0, b1;
  if (doScale) {
    b0 = *(const uint4*)Bgs;
    b1 = *(const uint4*)(Bgs + 32);
  } else {
    async16(BgC[0], &Bs[0][BlC[0]]);
    async16(BgC[1], &Bs[0][BlC[1]]);
  }
  __syncthreads();                   // asyncs drained; sm visible

  int p = 0;
  for (int kt = 0; kt < 4; ++kt) {
    if (doScale) {                   // thread's B k-col = w*8 (+32 for sub1)
      int kg = k0 + (kt << 6) + (w << 3);
      *(uint4*)&Bs[p][tid << 3] = scale_b8(b0, kg, smrow);
      *(uint4*)&Bs[p][2048 + (tid << 3)] = scale_b8(b1, kg + 32, smrow);
      __syncthreads();               // Bs[p] visible; As[p] asyncs complete
    } else if (kt > 0) {
      __syncthreads();               // buf p asyncs complete
    }
    if (kt + 1 < 4) {                // prefetch escapes the barrier drain
      int kk = (kt + 1) << 6;
      #pragma unroll
      for (int m = 0; m < 4; ++m) async16(AgC[m] + kk, &As[p ^ 1][AlC[m]]);
      if (doScale) {
        b0 = *(const uint4*)(Bgs + kk);
        b1 = *(const uint4*)(Bgs + kk + 32);
      } else {
        async16(BgC[0] + kk, &Bs[p ^ 1][BlC[0]]);
        async16(BgC[1] + kk, &Bs[p ^ 1][BlC[1]]);
      }
    }
    #pragma unroll
    for (int s = 0; s < 2; ++s) {
      short8 af[4], bfr[2];
      #pragma unroll
      for (int ms = 0; ms < 4; ++ms)
        af[ms] = *(const short8*)&As[p][(s << 12) + (quad << 10)
                                        + ((wm + ms * 16 + lrow) << 3)];
      #pragma unroll
      for (int ns = 0; ns < 2; ++ns)
        bfr[ns] = *(const short8*)&Bs[p][(s << 11) + (quad << 9)
                                         + ((wn + ns * 16 + lrow) << 3)];
      #pragma unroll
      for (int ms = 0; ms < 4; ++ms)
        #pragma unroll
        for (int ns = 0; ns < 2; ++ns)
          acc[ms][ns] = __builtin_amdgcn_mfma_f32_16x16x32_bf16(
              af[ms], bfr[ns], acc[ms][ns], 0, 0, 0);
    }
    p ^= 1;
  }
  // transposed bf16 store: P[z][n*256 + b]; lane holds 4 consecutive b
  size_t zb = (size_t)blockIdx.z * (size_t)STILE;
  #pragma unroll
  for (int ms = 0; ms < 4; ++ms)
    #pragma unroll
    for (int ns = 0; ns < 2; ++ns) {
      int b = (int)m0 + wm + ms * 16 + (quad << 2);
      int n = (int)n0 + wn + ns * 16 + lrow;
      uint2 pk;
      pk.x = pack2(acc[ms][ns][0], acc[ms][ns][1]);
      pk.y = pack2(acc[ms][ns][2], acc[ms][ns][3]);
      *(uint2*)&P[zb + (size_t)n * B_ + b] = pk;
    }
}

// ---- fused split-K reduce + squash, reading P^T[z][n][b] bf16.
// grid (96 c, 4 b-quarters); block 256 = 4 o-groups x 64 lanes; 1 b/lane.
__global__ void k_redsq(const u16* __restrict__ P, float* __restrict__ out,
                        u16* __restrict__ vT, float preScale, int last) {
  __shared__ float nsq_l[4][64];
  int c = blockIdx.x, bh = blockIdx.y;
  int lane = threadIdx.x & 63, og = threadIdx.x >> 6;
  int b = (bh << 6) + lane;
  int n0 = (c << 4) + (og << 2);
  float acc[4];
  #pragma unroll
  for (int oo = 0; oo < 4; ++oo) acc[oo] = 0.f;
  #pragma unroll
  for (int z = 0; z < ZSPLIT; ++z) {
    size_t base = (size_t)z * STILE + (size_t)n0 * B_ + b;
    #pragma unroll
    for (int oo = 0; oo < 4; ++oo)
      acc[oo] += bf2f(P[base + (size_t)oo * B_]);
  }
  #pragma unroll
  for (int oo = 0; oo < 4; ++oo) acc[oo] *= preScale;
  float q = acc[0] * acc[0] + acc[1] * acc[1] + acc[2] * acc[2] + acc[3] * acc[3];
  nsq_l[og][lane] = q;
  __syncthreads();
  float nsq = nsq_l[0][lane] + nsq_l[1][lane] + nsq_l[2][lane] + nsq_l[3][lane];
  float f = nsq / ((1.0f + nsq) * sqrtf(nsq));
  #pragma unroll
  for (int oo = 0; oo < 4; ++oo) acc[oo] *= f;
  if (last) {
    *(float4*)(out + (size_t)b * N_ + n0) = (float4){acc[0], acc[1], acc[2], acc[3]};
  } else {
    #pragma unroll
    for (int oo = 0; oo < 4; ++oo)
      vT[(size_t)(n0 + oo) * B_ + b] = f2bf(acc[oo]);
  }
}

// ---- GEMM2 + agreement fused, 128m x 64n tile, grid (30,24), K=256 =
// 4 x BK64 (2 BK32 sub-tiles per barrier), fully async staging.
__global__ __launch_bounds__(256) void gemm2_agree(
    const u16* __restrict__ A, const u16* __restrict__ Bt,
    const u16* __restrict__ WtT, float* __restrict__ bij) {
  const int K = 256;
  __shared__ u16 As[2][8192];   // chunked, same scheme as gemm1
  __shared__ u16 Bs[2][4096];
  int tid = threadIdx.x;
  long m0 = (long)blockIdx.x * 128, n0 = (long)blockIdx.y * 64;
  const u16* Ab = A + m0 * K;
  const u16* Bb = Bt + n0 * K;
  int w = tid >> 6, lane = tid & 63;
  int wm = (w >> 1) << 6, wn = (w & 1) << 5;
  int quad = lane >> 4, lrow = lane & 15;
  const u16* AgC[4]; int AlC[4];
  #pragma unroll
  for (int m = 0; m < 4; ++m) {
    int g16 = (m << 2) + w;
    AgC[m] = Ab + (long)(((g16 & 1) << 6) + lane) * K
             + (g16 >> 3) * 32 + ((g16 >> 1) & 3) * 8;
    AlC[m] = g16 << 9;
  }
  const u16* BgC[2]; int BlC[2];
  #pragma unroll
  for (int m = 0; m < 2; ++m) {
    int g8 = (m << 2) + w;
    BgC[m] = Bb + (long)lane * K + (g8 >> 2) * 32 + (g8 & 3) * 8;
    BlC[m] = g8 << 9;
  }
  floatx4 acc[4][2];
  #pragma unroll
  for (int a = 0; a < 4; ++a)
    #pragma unroll
    for (int b = 0; b < 2; ++b) acc[a][b] = (floatx4){0.f, 0.f, 0.f, 0.f};

  #pragma unroll
  for (int m = 0; m < 4; ++m) async16(AgC[m], &As[0][AlC[m]]);
  async16(BgC[0], &Bs[0][BlC[0]]);
  async16(BgC[1], &Bs[0][BlC[1]]);

  int p = 0;
  #pragma unroll
  for (int kt = 0; kt < 4; ++kt) {
    __syncthreads();                 // buf p asyncs complete
    if (kt + 1 < 4) {                // async prefetch escapes the drain
      int kk = (kt + 1) << 6;
      #pragma unroll
      for (int m = 0; m < 4; ++m) async16(AgC[m] + kk, &As[p ^ 1][AlC[m]]);
      async16(BgC[0] + kk, &Bs[p ^ 1][BlC[0]]);
      async16(BgC[1] + kk, &Bs[p ^ 1][BlC[1]]);
    }
    #pragma unroll
    for (int s = 0; s < 2; ++s) {
      short8 af[4], bfr[2];
      #pragma unroll
      for (int ms = 0; ms < 4; ++ms)
        af[ms] = *(const short8*)&As[p][(s << 12) + (quad << 10)
                                        + ((wm + ms * 16 + lrow) << 3)];
      #pragma unroll
      for (int ns = 0; ns < 2; ++ns)
        bfr[ns] = *(const short8*)&Bs[p][(s << 11) + (quad << 9)
                                         + ((wn + ns * 16 + lrow) << 3)];
      #pragma unroll
      for (int ms = 0; ms < 4; ++ms)
        #pragma unroll
        for (int ns = 0; ns < 2; ++ns)
          acc[ms][ns] = __builtin_amdgcn_mfma_f32_16x16x32_bf16(
              af[ms], bfr[ns], acc[ms][ns], 0, 0, 0);
    }
    p ^= 1;
  }
  // epilogue: per fragment, cols = one capsule c; 16 rows span <=2 routes r.
  #pragma unroll
  for (int ms = 0; ms < 4; ++ms) {
    int rowbase = (int)m0 + wm + ms * 16;          // wave-uniform
    int r_lo = rowbase / I_;
    int r_hi = (rowbase + 15) / I_;
    int bnd = (r_lo + 1) * I_;
    int rowl = rowbase + (quad << 2);
    #pragma unroll
    for (int ns = 0; ns < 2; ++ns) {
      int col = (int)n0 + wn + ns * 16 + lrow;
      uint2 wv = *(const uint2*)&WtT[(size_t)col * K1 + rowl];
      u16 h[4];
      h[0] = (u16)(wv.x & 0xffff); h[1] = (u16)(wv.x >> 16);
      h[2] = (u16)(wv.y & 0xffff); h[3] = (u16)(wv.y >> 16);
      float p0 = 0.f, p1 = 0.f;
      #pragma unroll
      for (int e = 0; e < 4; ++e) {
        float pr = acc[ms][ns][e] * bf2f(h[e]);
        if (rowl + e < bnd) p0 += pr; else p1 += pr;
      }
      #pragma unroll
      for (int off = 32; off > 0; off >>= 1) {
        p0 += __shfl_xor(p0, off);
        p1 += __shfl_xor(p1, off);
      }
      if (lane == 0) {
        int c = col >> 4;
        atomicAdd(&bij[c * R_ + r_lo], p0 * (1.0f / 256.0f));
        atomicAdd(&bij[c * R_ + r_hi], p1 * (1.0f / 256.0f));
      }
    }
  }
}

extern "C" void kernel_launch(void* const* d_in, const int* in_sizes, int n_in,
                              void* d_out, int out_size, void* d_ws, size_t ws_size,
                              hipStream_t stream) {
  const float* X = (const float*)d_in[0];   // fp32 [256,192,20]
  const float* W = (const float*)d_in[1];   // fp32 [192,96,16,20]
  float* out = (float*)d_out;               // fp32 [256,96,16]
  char* ws = (char*)d_ws;
  u16*  WtT = (u16*)(ws);                   // 11,796,480 B
  u16*  Xk  = (u16*)(ws + 11796480);        //  1,966,080 B
  u16*  xT  = (u16*)(ws + 13762560);        //  1,966,080 B
  u16*  vT  = (u16*)(ws + 15728640);        //    786,432 B
  u16*  Pb  = (u16*)(ws + 16515072);        // 15 z x 786,432 B = 11,796,480 B
  float* bij = (float*)(ws + 28311552);     //     73,728 B (c-major [c][r])

  k_prep<<<6018, 256, 0, stream>>>(W, X, WtT, Xk, xT, bij);

  for (int it = 0; it < 3; ++it) {
    // s partials: M=256,N=1536,K=3840, grid (2,24,15)=720, 4 BK64 iters.
    // iter 0: no scale in gemm1; uniform softmax 1/192 applied in redsq.
    gemm1<<<dim3(2, 24, ZSPLIT), 256, 0, stream>>>(Xk, WtT, bij, Pb, it > 0);
    k_redsq<<<dim3(96, 4), 256, 0, stream>>>(
        Pb, out, vT, it == 0 ? (1.0f / 192.0f) : 1.0f, it == 2);
    if (it < 2)
      gemm2_agree<<<dim3(30, 24), 256, 0, stream>>>(xT, vT, WtT, bij);
  }
}

// Round 5
// 149.090 us; speedup vs baseline: 1.3871x; 1.1675x over previous
//
#include <hip/hip_runtime.h>

// DigitCaps dynamic routing, B=256 R=192 C=96 O=16 I=20. fp32 in/out.
// u_hat never materialized. 9 dispatches (R0 proven structure) + sigma-swz:
//   prep: W->WtT bf16 k-major; X->Xk + xT; bij=0 (bij C-MAJOR [c][r])
//   gemm1 (x3): 128m x 64n tile, split-K=15 (kChunk 256 = 4 iters of BK64,
//     each iter = 2 BK32 sub-tiles sharing ONE barrier), grid (2,24,15)=720;
//     A async global_load_lds(16B); B: it0 fully async, else reg-prefetch +
//     wave-local softmax scale at LDS-write; double LDS; partials bf16
//     P^T[z][n][b]
//   redsq (x3): grid (96,4); split-K reduce (+preScale) + squash -> vT/out
//   gemm2_agree (x2): 128x64 tile, grid (30,24), fully async staging;
//     agreement in epilogue vs WtT, atomicAdd bij
// SIGMA-SWIZZLE (new): LDS chunk (row, kgroup q) stored at 16B-slot
// row*4 + sigma, sigma=(q+(row>>1))&3. Staging LDS dest stays LINEAR
// (global_load_lds requirement) with chunk order [row][sigma]; 4
// consecutive chunks = one row's 4 k-groups PERMUTED inside one 64B
// segment -> global coalescing identical to R0 (R4's row-major chunk
// order scattered sources 64x16B -> regressed). Frag read banks:
// 16 lanes -> 8 bank-quads x2 = 2-way (free) vs R0's 8-way (8.4M
// conflict cycles/dispatch). ds_write scale path: contiguous 1KB/wave.
// Lesson R1: __threadfence cross-block fusion = L2-writeback storm.
// Lesson R2/R3: 32x32 full-K tile = 2x L2/L3 traffic; split-K+TLP wins.
// Lesson R4: chunk order must keep 4-consecutive-chunks = one row.

#define R_ 192
#define C_ 96
#define O_ 16
#define I_ 20
#define B_ 256
#define K1 3840   // R*I
#define N_ 1536   // C*O
#define ZSPLIT 15
#define KCH 256       // K1/ZSPLIT; 4 iters of BK=64 (2x BK32 sub-tiles)
#define STILE 393216  // N_*B_ elements per z-slice

typedef unsigned short u16;
typedef __attribute__((ext_vector_type(8))) short short8;
typedef __attribute__((ext_vector_type(4))) float floatx4;

__device__ inline float bf2f(u16 h) {
  union { unsigned int u; float f; } x; x.u = ((unsigned int)h) << 16; return x.f;
}
__device__ inline u16 f2bf(float f) {
  union { float f; unsigned int u; } x; x.f = f;
  unsigned int r = x.u + 0x7FFFu + ((x.u >> 16) & 1u);
  return (u16)(r >> 16);
}
__device__ inline unsigned int pack2(float a, float b) {
  return (unsigned int)f2bf(a) | ((unsigned int)f2bf(b) << 16);
}
// async 16B/lane global->LDS; lds base wave-uniform (lane scatters +16B)
__device__ inline void async16(const u16* g, u16* l) {
  __builtin_amdgcn_global_load_lds(
      (__attribute__((address_space(1))) void*)(unsigned long long)g,
      (__attribute__((address_space(3))) void*)(unsigned int)(unsigned long long)l,
      16, 0, 0);
}

// ---- fused prep: WtT gather (5760 blocks, 4 elems/thr); X cast+transpose
// (240); bij=0 c-major (18)
__global__ void k_prep(const float* __restrict__ W, const float* __restrict__ X,
                       u16* __restrict__ WtT, u16* __restrict__ Xk,
                       u16* __restrict__ xT, float* __restrict__ bij) {
  int bid = blockIdx.x;
  if (bid < 5760) {
    int t = (bid * 256 + threadIdx.x) << 2;    // 4-group stays in one n
    int n = t / K1, k = t - n * K1;
    int c = n >> 4, o = n & 15;
    const float* Wn = W + (size_t)(c * O_ + o) * I_;
    u16 h[4];
    #pragma unroll
    for (int e = 0; e < 4; ++e) {
      int ke = k + e, r = ke / I_, i = ke - r * I_;
      h[e] = f2bf(Wn[(size_t)r * (C_ * O_ * I_) + i]);
    }
    ushort4 o4; o4.x = h[0]; o4.y = h[1]; o4.z = h[2]; o4.w = h[3];
    *(ushort4*)&WtT[t] = o4;
  } else if (bid < 6000) {
    __shared__ u16 tile[64][72];
    int idx = bid - 5760;
    int kb = (idx % 60) << 6, bb = (idx / 60) << 6;
    int brow = threadIdx.x >> 4;          // 0..15
    int kq = (threadIdx.x & 15) << 2;     // 0..60 step 4
    #pragma unroll
    for (int p = 0; p < 4; ++p) {
      int bl = p * 16 + brow;
      float4 v = *(const float4*)(X + (size_t)(bb + bl) * K1 + kb + kq);
      ushort4 h;
      h.x = f2bf(v.x); h.y = f2bf(v.y); h.z = f2bf(v.z); h.w = f2bf(v.w);
      *(ushort4*)(Xk + (size_t)(bb + bl) * K1 + kb + kq) = h;
      tile[kq + 0][bl] = h.x;
      tile[kq + 1][bl] = h.y;
      tile[kq + 2][bl] = h.z;
      tile[kq + 3][bl] = h.w;
    }
    __syncthreads();
    int kr = threadIdx.x >> 3;            // 0..31
    int bq = (threadIdx.x & 7) << 3;      // 0..56 step 8
    #pragma unroll
    for (int q = 0; q < 2; ++q) {
      int kl = q * 32 + kr;
      *(uint4*)(xT + (size_t)(kb + kl) * B_ + bb + bq) = *(const uint4*)&tile[kl][bq];
    }
  } else {
    int t = ((bid - 6000) * 256 + threadIdx.x) << 2;  // bij: 18,432 floats
    if (t < R_ * C_) *(float4*)&bij[t] = (float4){0.f, 0.f, 0.f, 0.f};
  }
}

// scale 8 k-contiguous bf16 (global k = kg..kg+7) by softmax row(s)
__device__ inline uint4 scale_b8(uint4 raw, int kg, const float* smrow) {
  int r0 = kg / I_;
  int bnd = (r0 + 1) * I_ - kg;                // elements j<bnd use r0
  float s0 = smrow[r0];
  float s1 = smrow[(r0 + 1 < R_) ? r0 + 1 : R_ - 1];
  union { uint4 q; u16 h[8]; } u; u.q = raw;
  #pragma unroll
  for (int j = 0; j < 8; ++j)
    u.h[j] = f2bf(bf2f(u.h[j]) * ((j < bnd) ? s0 : s1));
  return u.q;
}

// LDS sigma-swizzle layout (per buffer, per matrix):
//   elem(sub, row, q, j) -> sub*(rows*32) + row*32 + ((q+(row>>1))&3)*8 + j
// Chunk id gc = sub*(rows*4) + row*4 + sigma; staged LINEARLY at gc*16B.
// Inverse (for staging source): row = cc>>2, sigma = cc&3,
//   q = (sigma - ((row>>1)&3)) & 3. Per 4 consecutive chunks: one row,
//   4 k-groups permuted inside one 64B global segment (full coalescing).

// ---- GEMM1: P^T[z][n][b] bf16 = (Xk[256,3840] x (c*WtT)[1536,3840]^T),
// k-chunk z (256 = 4 x BK64; each BK64 = 2 BK32 sub-tiles, ONE barrier).
// 128m x 64n tile, 4 waves of 64x32, grid (2,24,15)=720.
__global__ __launch_bounds__(256) void gemm1(
    const u16* __restrict__ A, const u16* __restrict__ Bt,
    const float* __restrict__ bij, u16* __restrict__ P, int doScale) {
  __shared__ u16 As[2][8192];   // 32 KB (sigma-swz)
  __shared__ u16 Bs[2][4096];   // 16 KB (sigma-swz)
  __shared__ float sm[4][192];
  int tid = threadIdx.x;
  int w = tid >> 6, lane = tid & 63;
  if (doScale) {  // wave-local softmax: wave w owns capsule (by<<2)+w
    int c = (blockIdx.y << 2) + w;
    float e0 = bij[c * R_ + lane];
    float e1 = bij[c * R_ + lane + 64];
    float e2 = bij[c * R_ + lane + 128];
    float mx = fmaxf(e0, fmaxf(e1, e2));
    #pragma unroll
    for (int off = 32; off > 0; off >>= 1) mx = fmaxf(mx, __shfl_xor(mx, off));
    e0 = expf(e0 - mx); e1 = expf(e1 - mx); e2 = expf(e2 - mx);
    float s = e0 + e1 + e2;
    #pragma unroll
    for (int off = 32; off > 0; off >>= 1) s += __shfl_xor(s, off);
    float inv = 1.0f / s;
    sm[w][lane] = e0 * inv;
    sm[w][lane + 64] = e1 * inv;
    sm[w][lane + 128] = e2 * inv;
  }

  long m0 = (long)blockIdx.x * 128, n0 = (long)blockIdx.y * 64;
  int k0 = blockIdx.z * KCH;
  const u16* Ab = A + m0 * K1 + k0;
  const u16* Bb = Bt + n0 * K1 + k0;
  // staging source permutation (wave-call covers 64 consecutive chunks):
  // lane l -> row_off = l>>2, k-group q_s = ((l&3) - ((l>>3)&3)) & 3.
  int q_s = ((lane & 3) - ((lane >> 3) & 3)) & 3;
  // A: call m (0..3): row = ((m&1)<<6) + (w<<4) + (l>>2);
  //    col = (m>>1)*32 + q_s*8; LDS base elem = (m<<11)+(w<<9).
  const u16* AgC[4]; int AlC[4];
  #pragma unroll
  for (int m = 0; m < 4; ++m) {
    AgC[m] = Ab + (long)(((m & 1) << 6) + (w << 4) + (lane >> 2)) * K1
             + ((m >> 1) << 5) + (q_s << 3);
    AlC[m] = (m << 11) + (w << 9);
  }
  // B async (it0): call m (0..1): row = (w<<4)+(l>>2); col = m*32 + q_s*8.
  const u16* BgC[2]; int BlC[2];
  #pragma unroll
  for (int m = 0; m < 2; ++m) {
    BgC[m] = Bb + (long)((w << 4) + (lane >> 2)) * K1 + (m << 5) + (q_s << 3);
    BlC[m] = (m << 11) + (w << 9);
  }
  // doScale reg-staging: thread tid -> chunk tid of sub0 (+ sub1 at +2048):
  // row = tid>>2, qD = ((tid&3) - ((tid>>3)&3)) & 3; write = linear 16B.
  int rowD = tid >> 2;
  int qD = ((tid & 3) - ((tid >> 3) & 3)) & 3;
  const u16* Bgs = Bb + (long)rowD * K1 + (qD << 3);
  const float* smrow = &sm[w][0];         // capsule of row rowD = rowD>>4 = w
  int wm = (w >> 1) << 6, wn = (w & 1) << 5;
  int quad = lane >> 4, lrow = lane & 15;
  int swz = ((quad + (lrow >> 1)) & 3) << 3;   // frag-read sigma slot
  floatx4 acc[4][2];
  #pragma unroll
  for (int a = 0; a < 4; ++a)
    #pragma unroll
    for (int b = 0; b < 2; ++b) acc[a][b] = (floatx4){0.f, 0.f, 0.f, 0.f};

  // kt=0 staging: both sub-tiles
  #pragma unroll
  for (int m = 0; m < 4; ++m) async16(AgC[m], &As[0][AlC[m]]);
  uint4 b0, b1;
  if (doScale) {
    b0 = *(const uint4*)Bgs;
    b1 = *(const uint4*)(Bgs + 32);
  } else {
    async16(BgC[0], &Bs[0][BlC[0]]);
    async16(BgC[1], &Bs[0][BlC[1]]);
  }
  __syncthreads();                   // asyncs drained; sm visible

  int p = 0;
  for (int kt = 0; kt < 4; ++kt) {
    if (doScale) {                   // thread's B k-cols: qD*8 (+32 sub1)
      int kg = k0 + (kt << 6) + (qD << 3);
      *(uint4*)&Bs[p][tid << 3] = scale_b8(b0, kg, smrow);
      *(uint4*)&Bs[p][2048 + (tid << 3)] = scale_b8(b1, kg + 32, smrow);
      __syncthreads();               // Bs[p] visible; As[p] asyncs complete
    } else if (kt > 0) {
      __syncthreads();               // buf p asyncs complete
    }
    if (kt + 1 < 4) {                // prefetch escapes the barrier drain
      int kk = (kt + 1) << 6;
      #pragma unroll
      for (int m = 0; m < 4; ++m) async16(AgC[m] + kk, &As[p ^ 1][AlC[m]]);
      if (doScale) {
        b0 = *(const uint4*)(Bgs + kk);
        b1 = *(const uint4*)(Bgs + kk + 32);
      } else {
        async16(BgC[0] + kk, &Bs[p ^ 1][BlC[0]]);
        async16(BgC[1] + kk, &Bs[p ^ 1][BlC[1]]);
      }
    }
    #pragma unroll
    for (int s = 0; s < 2; ++s) {
      short8 af[4], bfr[2];
      #pragma unroll
      for (int ms = 0; ms < 4; ++ms)
        af[ms] = *(const short8*)&As[p][(s << 12)
                                        + ((wm + ms * 16 + lrow) << 5) + swz];
      #pragma unroll
      for (int ns = 0; ns < 2; ++ns)
        bfr[ns] = *(const short8*)&Bs[p][(s << 11)
                                         + ((wn + ns * 16 + lrow) << 5) + swz];
      #pragma unroll
      for (int ms = 0; ms < 4; ++ms)
        #pragma unroll
        for (int ns = 0; ns < 2; ++ns)
          acc[ms][ns] = __builtin_amdgcn_mfma_f32_16x16x32_bf16(
              af[ms], bfr[ns], acc[ms][ns], 0, 0, 0);
    }
    p ^= 1;
  }
  // transposed bf16 store: P[z][n*256 + b]; lane holds 4 consecutive b
  size_t zb = (size_t)blockIdx.z * (size_t)STILE;
  #pragma unroll
  for (int ms = 0; ms < 4; ++ms)
    #pragma unroll
    for (int ns = 0; ns < 2; ++ns) {
      int b = (int)m0 + wm + ms * 16 + (quad << 2);
      int n = (int)n0 + wn + ns * 16 + lrow;
      uint2 pk;
      pk.x = pack2(acc[ms][ns][0], acc[ms][ns][1]);
      pk.y = pack2(acc[ms][ns][2], acc[ms][ns][3]);
      *(uint2*)&P[zb + (size_t)n * B_ + b] = pk;
    }
}

// ---- fused split-K reduce + squash, reading P^T[z][n][b] bf16.
// grid (96 c, 4 b-quarters); block 256 = 4 o-groups x 64 lanes; 1 b/lane.
__global__ void k_redsq(const u16* __restrict__ P, float* __restrict__ out,
                        u16* __restrict__ vT, float preScale, int last) {
  __shared__ float nsq_l[4][64];
  int c = blockIdx.x, bh = blockIdx.y;
  int lane = threadIdx.x & 63, og = threadIdx.x >> 6;
  int b = (bh << 6) + lane;
  int n0 = (c << 4) + (og << 2);
  float acc[4];
  #pragma unroll
  for (int oo = 0; oo < 4; ++oo) acc[oo] = 0.f;
  #pragma unroll
  for (int z = 0; z < ZSPLIT; ++z) {
    size_t base = (size_t)z * STILE + (size_t)n0 * B_ + b;
    #pragma unroll
    for (int oo = 0; oo < 4; ++oo)
      acc[oo] += bf2f(P[base + (size_t)oo * B_]);
  }
  #pragma unroll
  for (int oo = 0; oo < 4; ++oo) acc[oo] *= preScale;
  float q = acc[0] * acc[0] + acc[1] * acc[1] + acc[2] * acc[2] + acc[3] * acc[3];
  nsq_l[og][lane] = q;
  __syncthreads();
  float nsq = nsq_l[0][lane] + nsq_l[1][lane] + nsq_l[2][lane] + nsq_l[3][lane];
  float f = nsq / ((1.0f + nsq) * sqrtf(nsq));
  #pragma unroll
  for (int oo = 0; oo < 4; ++oo) acc[oo] *= f;
  if (last) {
    *(float4*)(out + (size_t)b * N_ + n0) = (float4){acc[0], acc[1], acc[2], acc[3]};
  } else {
    #pragma unroll
    for (int oo = 0; oo < 4; ++oo)
      vT[(size_t)(n0 + oo) * B_ + b] = f2bf(acc[oo]);
  }
}

// ---- GEMM2 + agreement fused, 128m x 64n tile, grid (30,24), K=256 =
// 4 x BK64 (2 BK32 sub-tiles per barrier), fully async staging; sigma-swz.
__global__ __launch_bounds__(256) void gemm2_agree(
    const u16* __restrict__ A, const u16* __restrict__ Bt,
    const u16* __restrict__ WtT, float* __restrict__ bij) {
  const int K = 256;
  __shared__ u16 As[2][8192];
  __shared__ u16 Bs[2][4096];
  int tid = threadIdx.x;
  long m0 = (long)blockIdx.x * 128, n0 = (long)blockIdx.y * 64;
  const u16* Ab = A + m0 * K;
  const u16* Bb = Bt + n0 * K;
  int w = tid >> 6, lane = tid & 63;
  int wm = (w >> 1) << 6, wn = (w & 1) << 5;
  int quad = lane >> 4, lrow = lane & 15;
  int swz = ((quad + (lrow >> 1)) & 3) << 3;
  int q_s = ((lane & 3) - ((lane >> 3) & 3)) & 3;
  const u16* AgC[4]; int AlC[4];
  #pragma unroll
  for (int m = 0; m < 4; ++m) {
    AgC[m] = Ab + (long)(((m & 1) << 6) + (w << 4) + (lane >> 2)) * K
             + ((m >> 1) << 5) + (q_s << 3);
    AlC[m] = (m << 11) + (w << 9);
  }
  const u16* BgC[2]; int BlC[2];
  #pragma unroll
  for (int m = 0; m < 2; ++m) {
    BgC[m] = Bb + (long)((w << 4) + (lane >> 2)) * K + (m << 5) + (q_s << 3);
    BlC[m] = (m << 11) + (w << 9);
  }
  floatx4 acc[4][2];
  #pragma unroll
  for (int a = 0; a < 4; ++a)
    #pragma unroll
    for (int b = 0; b < 2; ++b) acc[a][b] = (floatx4){0.f, 0.f, 0.f, 0.f};

  #pragma unroll
  for (int m = 0; m < 4; ++m) async16(AgC[m], &As[0][AlC[m]]);
  async16(BgC[0], &Bs[0][BlC[0]]);
  async16(BgC[1], &Bs[0][BlC[1]]);

  int p = 0;
  #pragma unroll
  for (int kt = 0; kt < 4; ++kt) {
    __syncthreads();                 // buf p asyncs complete
    if (kt + 1 < 4) {                // async prefetch escapes the drain
      int kk = (kt + 1) << 6;
      #pragma unroll
      for (int m = 0; m < 4; ++m) async16(AgC[m] + kk, &As[p ^ 1][AlC[m]]);
      async16(BgC[0] + kk, &Bs[p ^ 1][BlC[0]]);
      async16(BgC[1] + kk, &Bs[p ^ 1][BlC[1]]);
    }
    #pragma unroll
    for (int s = 0; s < 2; ++s) {
      short8 af[4], bfr[2];
      #pragma unroll
      for (int ms = 0; ms < 4; ++ms)
        af[ms] = *(const short8*)&As[p][(s << 12)
                                        + ((wm + ms * 16 + lrow) << 5) + swz];
      #pragma unroll
      for (int ns = 0; ns < 2; ++ns)
        bfr[ns] = *(const short8*)&Bs[p][(s << 11)
                                         + ((wn + ns * 16 + lrow) << 5) + swz];
      #pragma unroll
      for (int ms = 0; ms < 4; ++ms)
        #pragma unroll
        for (int ns = 0; ns < 2; ++ns)
          acc[ms][ns] = __builtin_amdgcn_mfma_f32_16x16x32_bf16(
              af[ms], bfr[ns], acc[ms][ns], 0, 0, 0);
    }
    p ^= 1;
  }
  // epilogue: per fragment, cols = one capsule c; 16 rows span <=2 routes r.
  #pragma unroll
  for (int ms = 0; ms < 4; ++ms) {
    int rowbase = (int)m0 + wm + ms * 16;          // wave-uniform
    int r_lo = rowbase / I_;
    int r_hi = (rowbase + 15) / I_;
    int bnd = (r_lo + 1) * I_;
    int rowl = rowbase + (quad << 2);
    #pragma unroll
    for (int ns = 0; ns < 2; ++ns) {
      int col = (int)n0 + wn + ns * 16 + lrow;
      uint2 wv = *(const uint2*)&WtT[(size_t)col * K1 + rowl];
      u16 h[4];
      h[0] = (u16)(wv.x & 0xffff); h[1] = (u16)(wv.x >> 16);
      h[2] = (u16)(wv.y & 0xffff); h[3] = (u16)(wv.y >> 16);
      float p0 = 0.f, p1 = 0.f;
      #pragma unroll
      for (int e = 0; e < 4; ++e) {
        float pr = acc[ms][ns][e] * bf2f(h[e]);
        if (rowl + e < bnd) p0 += pr; else p1 += pr;
      }
      #pragma unroll
      for (int off = 32; off > 0; off >>= 1) {
        p0 += __shfl_xor(p0, off);
        p1 += __shfl_xor(p1, off);
      }
      if (lane == 0) {
        int c = col >> 4;
        atomicAdd(&bij[c * R_ + r_lo], p0 * (1.0f / 256.0f));
        atomicAdd(&bij[c * R_ + r_hi], p1 * (1.0f / 256.0f));
      }
    }
  }
}

extern "C" void kernel_launch(void* const* d_in, const int* in_sizes, int n_in,
                              void* d_out, int out_size, void* d_ws, size_t ws_size,
                              hipStream_t stream) {
  const float* X = (const float*)d_in[0];   // fp32 [256,192,20]
  const float* W = (const float*)d_in[1];   // fp32 [192,96,16,20]
  float* out = (float*)d_out;               // fp32 [256,96,16]
  char* ws = (char*)d_ws;
  u16*  WtT = (u16*)(ws);                   // 11,796,480 B
  u16*  Xk  = (u16*)(ws + 11796480);        //  1,966,080 B
  u16*  xT  = (u16*)(ws + 13762560);        //  1,966,080 B
  u16*  vT  = (u16*)(ws + 15728640);        //    786,432 B
  u16*  Pb  = (u16*)(ws + 16515072);        // 15 z x 786,432 B = 11,796,480 B
  float* bij = (float*)(ws + 28311552);     //     73,728 B (c-major [c][r])

  k_prep<<<6018, 256, 0, stream>>>(W, X, WtT, Xk, xT, bij);

  for (int it = 0; it < 3; ++it) {
    // s partials: M=256,N=1536,K=3840, grid (2,24,15)=720, 4 BK64 iters.
    // iter 0: no scale in gemm1; uniform softmax 1/192 applied in redsq.
    gemm1<<<dim3(2, 24, ZSPLIT), 256, 0, stream>>>(Xk, WtT, bij, Pb, it > 0);
    k_redsq<<<dim3(96, 4), 256, 0, stream>>>(
        Pb, out, vT, it == 0 ? (1.0f / 192.0f) : 1.0f, it == 2);
    if (it < 2)
      gemm2_agree<<<dim3(30, 24), 256, 0, stream>>>(xT, vT, WtT, bij);
  }
}